// Round 8
// baseline (6187.572 us; speedup 1.0000x reference)
//
#include <hip/hip_runtime.h>
#include <math.h>

// Problem constants
#define BB 32
#define TT 512
#define II 96

// d_out region offsets (floats)
#define O_HSEQ  1048576
#define O_AIN   26214400
#define O_ACM   51380224
#define O_ATTN  76546048

// ws layout (floats)
#define WS_WEFF 0
#define WS_UT   49152
#define WS_WQT  73728
#define WS_WKT  98304
#define WS_VC   122880          /* [2][32][6][256] = 98304 */
#define WS_QK   221184          /* [2][32][192]    = 12288 */
#define WS_FLAG 233472          /* 256 words */
#define WS_COOP_FLOATS 233728

// lgkm-only barrier: orders LDS producer->consumer without draining vmcnt
#define LBAR() asm volatile("s_waitcnt lgkmcnt(0)\n\ts_barrier" ::: "memory")

__device__ __forceinline__ float sysldf(const float* p) {
  return __hip_atomic_load(p, __ATOMIC_RELAXED, __HIP_MEMORY_SCOPE_SYSTEM);
}
__device__ __forceinline__ void sysstf(float* p, float v) {
  __hip_atomic_store(p, v, __ATOMIC_RELAXED, __HIP_MEMORY_SCOPE_SYSTEM);
}
__device__ __forceinline__ unsigned sysld32(const unsigned* p) {
  return __hip_atomic_load(p, __ATOMIC_RELAXED, __HIP_MEMORY_SCOPE_SYSTEM);
}
__device__ __forceinline__ void sysst32(unsigned* p, unsigned v) {
  __hip_atomic_store(p, v, __ATOMIC_RELAXED, __HIP_MEMORY_SCOPE_SYSTEM);
}

// ---------------------------------------------------------------------------
// K0: build Weff[m] = W_in[m] @ W_ip[m]  (m=0..3) and pre-transpose U, W_Q, W_K
// ---------------------------------------------------------------------------
__global__ __launch_bounds__(256) void rim_weff(
    const float* __restrict__ Wtask, const float* __restrict__ Wsens,
    const float* __restrict__ Wip,
    const float* __restrict__ U, const float* __restrict__ WQ, const float* __restrict__ WK,
    float* __restrict__ Weff, float* __restrict__ Ut, float* __restrict__ WQt, float* __restrict__ WKt)
{
  __shared__ float row[256];
  const int bidx = blockIdx.x;
  const int tid = threadIdx.x;
  if (bidx < 192) {
    int m, i;
    if (bidx < 32)       { m = 0; i = bidx; }
    else if (bidx < 64)  { m = 1; i = bidx - 32; }
    else if (bidx < 128) { m = 2; i = bidx - 64; }
    else                 { m = 3; i = bidx - 128; }
    row[tid] = (m < 2) ? Wtask[(m * 32 + i) * 256 + tid]
                       : Wsens[((m - 2) * 64 + i) * 256 + tid];
    __syncthreads();
    float acc = 0.f;
    const float* wip = Wip + m * 65536 + tid;
    #pragma unroll 8
    for (int j = 0; j < 256; ++j) acc += row[j] * wip[j * 256];
    const int base = (m == 0) ? 0 : (m == 1) ? 8192 : (m == 2) ? 16384 : 32768;
    Weff[base + i * 256 + tid] = acc;
  } else {
    const int p = bidx - 192;       // 0..95
    const int m = p >> 4, r = p & 15;
    Ut [(m * 16 + r) * 256 + tid] = U [m * 4096 + tid * 16 + r];
    WQt[(m * 16 + r) * 256 + tid] = WQ[m * 4096 + tid * 16 + r];
    WKt[(m * 16 + r) * 256 + tid] = WK[m * 4096 + tid * 16 + r];
  }
}

// ---------------------------------------------------------------------------
// K1: parallel Ain_seq output (independent of the recurrence)
// ---------------------------------------------------------------------------
__global__ __launch_bounds__(256) void rim_pre(
    const float* __restrict__ x,
    const float* __restrict__ Wtask, const float* __restrict__ Wsens,
    float* __restrict__ Ain)
{
  __shared__ float xr[16][96];
  const int tid = threadIdx.x;
  const int rb0 = blockIdx.x * 16;
  for (int idx = tid; idx < 16 * 96; idx += 256) {
    int r = idx / 96, c = idx % 96;
    int rb = rb0 + r; int t = rb >> 5, b = rb & 31;
    xr[r][c] = x[(b * TT + t) * II + c];
  }
  __syncthreads();
  const int h = tid;
  float acc[16];

  for (int m = 0; m < 4; ++m) {
    const int cnt  = (m < 2) ? 32 : 64;
    const int xoff = (m < 2) ? 64 : 0;
    const float* W = (m < 2) ? (Wtask + m * 32 * 256) : (Wsens + (m - 2) * 64 * 256);
    #pragma unroll
    for (int r = 0; r < 16; ++r) acc[r] = 0.f;
    for (int i = 0; i < cnt; ++i) {
      float w = W[i * 256 + h];
      #pragma unroll
      for (int r = 0; r < 16; ++r) acc[r] += xr[r][xoff + i] * w;
    }
    #pragma unroll
    for (int r = 0; r < 16; ++r) {
      int rb = rb0 + r; int t = rb >> 5, b = rb & 31;
      Ain[((t * 32 + b) * 6 + m) * 256 + h] = acc[r];
    }
  }
  #pragma unroll
  for (int r = 0; r < 16; ++r) {
    int rb = rb0 + r; int t = rb >> 5, b = rb & 31;
    Ain[((t * 32 + b) * 6 + 4) * 256 + h] = 0.f;
    Ain[((t * 32 + b) * 6 + 5) * 256 + h] = 0.f;
  }
}

// ---------------------------------------------------------------------------
// K2: cooperative recurrence, 4 BATCHES PER BLOCK.
// 48 blocks = (m, batch-group-of-4), 512 threads.
// Phase A: compute+publish Vc/QK for 4 batches back-to-back.
// ONE drain + ONE flag + ONE poll + bulk loads per 4 batch-steps.
// W_V half-column register-stationary (shared by all 4 batches).
// ---------------------------------------------------------------------------
__global__ __launch_bounds__(512, 2) void rim_step(
    const float* __restrict__ x,
    const float* __restrict__ Vr, const float* __restrict__ WV,
    const float* __restrict__ bip, const float* __restrict__ cbias,
    const float* __restrict__ UtW, const float* __restrict__ WQtW,
    const float* __restrict__ WKtW, const float* __restrict__ WeffW,
    float* __restrict__ VcG, float* __restrict__ QKG,
    unsigned* __restrict__ seqG,
    float* __restrict__ Hseq, float* __restrict__ Acm, float* __restrict__ attnO)
{
  __shared__ float Hl[4][256];
  __shared__ float Hin[4][256];
  __shared__ float inpl[4][2][256];
  __shared__ float xl[4][2][96];
  __shared__ float qkl[4][192];
  __shared__ float attnl[4][40];
  __shared__ float biasl[256];
  __shared__ float Vcp1[256];
  __shared__ float tmpUr[16];
  __shared__ float Utl[16][256];
  __shared__ float Vrl[16][256];
  __shared__ float WQtl[16][257];   // +1 pad (16-lane group reads)
  __shared__ float WKtl[16][257];
  __shared__ float Weffl[64][256];

  const int bid = blockIdx.x;
  const int m  = bid >> 3;       // 0..5
  const int g  = bid & 7;        // 0..7
  const int b0 = g * 4;
  const int tid = threadIdx.x;
  const int g32 = tid >> 5, l32 = tid & 31;
  const int g16 = tid >> 4, l16 = tid & 15;
  const int w64 = tid >> 6, lane = tid & 63;
  const int h_out = tid & 255, p = tid >> 8;

  const int cnt  = (m < 2) ? 32 : 64;
  const int xoff = (m < 2) ? 64 : 0;
  const int wbase = (m == 0) ? 0 : (m == 1) ? 8192 : (m == 2) ? 16384 : 32768;

  // ---- init: stage per-module weights ----
  for (int i = tid; i < 4096; i += 512) {
    int r = i >> 8, c = i & 255;
    Utl [r][c] = UtW [m * 4096 + i];
    Vrl [r][c] = Vr  [m * 4096 + i];
    WQtl[r][c] = WQtW[m * 4096 + i];
    WKtl[r][c] = WKtW[m * 4096 + i];
  }
  if (m < 4)
    for (int i = tid; i < cnt * 256; i += 512)
      ((float*)Weffl)[i] = WeffW[wbase + i];
  if (tid < 256) biasl[tid] = bip[m * 256 + tid] + cbias[m * 256 + tid];
  for (int i = tid; i < 1024; i += 512) Hl[i >> 8][i & 255] = 0.f;

  float xreg = 0.f;
  if (m < 4 && tid < 384) {
    const int bi = tid / 96, c = tid % 96;
    xl[bi][0][c] = x[((size_t)(b0 + bi) * TT + 0) * II + c];
    xreg         = x[((size_t)(b0 + bi) * TT + 1) * II + c];
  }
  // W_V half-column (shared across batches): w[j] = WV[m][p*128+j][h_out]
  float w[128];
  #pragma unroll
  for (int j = 0; j < 128; ++j)
    w[j] = WV[((size_t)(m * 256 + p * 128 + j)) * 256 + h_out];
  __syncthreads();
  // inp for t=0 (4 batches)
  if (m < 4 && tid < 256) {
    #pragma unroll
    for (int bi = 0; bi < 4; ++bi) {
      float a = 0.f;
      for (int i = 0; i < cnt; ++i) a += xl[bi][0][xoff + i] * Weffl[i][tid];
      inpl[bi][0][tid] = a;
    }
  }
  __syncthreads();

  float accVcS[4];
  for (int t = 0; t < TT; ++t) {
    const int buf = t & 1, nb = buf ^ 1;
    const unsigned target = (unsigned)(t + 1);
    const int vcbase = (buf * 32 + b0) * 1536;   // + bi*1536 + mm*256
    const int qkbase = (buf * 32 + b0) * 192;    // contiguous over bi

    // x rotate + 2-step prefetch
    if (m < 4 && tid < 384) {
      const int bi = tid / 96, c = tid % 96;
      xl[bi][nb][c] = xreg;
      xreg = (t + 2 < TT) ? x[((size_t)(b0 + bi) * TT + t + 2) * II + c] : 0.f;
    }

    // ================= Phase A: 4 batches compute + publish =================
    #pragma unroll
    for (int bi = 0; bi < 4; ++bi) {
      // publish full Vc of previous batch (needs Vcp1 from its P3)
      if (bi > 0 && tid < 256)
        sysstf(&VcG[vcbase + (bi - 1) * 1536 + m * 256 + tid],
               accVcS[bi - 1] + Vcp1[tid]);
      // P1: tmpUr[r] = sum_h Hl[bi][h] * U[m][h][r]
      {
        float s = 0.f;
        const float* up = &Utl[g32][0];
        const float* hp = &Hl[bi][0];
        #pragma unroll
        for (int h = l32; h < 256; h += 32) s += hp[h] * up[h];
        #pragma unroll
        for (int off = 16; off; off >>= 1) s += __shfl_down(s, off, 32);
        if (l32 == 0) tmpUr[g32] = s;
      }
      LBAR();
      // P2: Hin = tanh(inp + rec + bias)
      if (tid < 256) {
        float rec = 0.f;
        #pragma unroll
        for (int r = 0; r < 16; ++r) rec += tmpUr[r] * Vrl[r][tid];
        float inp = (m < 4) ? inpl[bi][buf][tid] : 0.f;
        Hin[bi][tid] = tanhf(inp + rec + biasl[tid]);
      }
      LBAR();
      // P3: QK rows publish + Vc half-dot
      {
        const int r = g16 & 15;
        const float* wp = (g16 < 16) ? &WQtl[r][0] : &WKtl[r][0];
        const float* hp = &Hin[bi][0];
        float s = 0.f;
        #pragma unroll
        for (int j = 0; j < 16; ++j) { int h = l16 + 16 * j; s += hp[h] * wp[h]; }
        s += __shfl_down(s, 8, 16);
        s += __shfl_down(s, 4, 16);
        s += __shfl_down(s, 2, 16);
        s += __shfl_down(s, 1, 16);
        if (l16 == 0)
          sysstf(&QKG[qkbase + bi * 192 + ((g16 < 16) ? 0 : 96) + m * 16 + r], s);
      }
      {
        float acc = 0.f;
        const float4* h4 = (const float4*)&Hin[bi][p * 128];
        #pragma unroll
        for (int q = 0; q < 32; ++q) {
          float4 hv = h4[q];
          acc += hv.x * w[4 * q] + hv.y * w[4 * q + 1]
               + hv.z * w[4 * q + 2] + hv.w * w[4 * q + 3];
        }
        accVcS[bi] = acc;
        if (p == 1) Vcp1[h_out] = acc;
      }
      LBAR();
    }
    if (tid < 256)
      sysstf(&VcG[vcbase + 3 * 1536 + m * 256 + tid], accVcS[3] + Vcp1[tid]);

    // ================= drain + flag + poll (ONCE per 4 steps) ===============
    asm volatile("s_waitcnt vmcnt(0)" ::: "memory");
    LBAR();
    if (tid == 0) sysst32(&seqG[m * 8 + g], target);
    if (w64 == 0 && lane < 6)
      while (sysld32(&seqG[lane * 8 + g]) < target) { }
    LBAR();

    // ================= Phase B: bulk loads + inp(t+1) + attention ===========
    float vA[4][6];
    if (tid < 256) {
      #pragma unroll
      for (int bi = 0; bi < 4; ++bi)
        #pragma unroll
        for (int mm = 0; mm < 6; ++mm)
          vA[bi][mm] = sysldf(&VcG[vcbase + bi * 1536 + mm * 256 + tid]);
    } else {
      const int f0 = (tid - 256) * 3;
      float q0 = sysldf(&QKG[qkbase + f0]);
      float q1 = sysldf(&QKG[qkbase + f0 + 1]);
      float q2 = sysldf(&QKG[qkbase + f0 + 2]);
      if (m < 4) {   // inp(t+1) for 4 batches, hidden under load latency
        const int h = tid - 256;
        #pragma unroll
        for (int bi = 0; bi < 4; ++bi) {
          float a = 0.f;
          for (int i = 0; i < cnt; ++i) a += xl[bi][nb][xoff + i] * Weffl[i][h];
          inpl[bi][nb][h] = a;
        }
      }
      ((float*)qkl)[f0]     = q0;
      ((float*)qkl)[f0 + 1] = q1;
      ((float*)qkl)[f0 + 2] = q2;
    }
    LBAR();

    // attention: wave (4+bi) handles batch bi (in-wave shfl softmax)
    if (w64 >= 4 && lane < 36) {
      const int bi = w64 - 4;
      const int mm6 = lane / 6, nn = lane % 6;
      const float* qw = &qkl[bi][mm6 * 16];
      const float* kw = &qkl[bi][96 + nn * 16];
      float s = 0.f;
      #pragma unroll
      for (int k = 0; k < 16; ++k) s += qw[k] * kw[k];
      s *= 0.25f;
      float mx = s;
      #pragma unroll
      for (int d = 1; d < 6; ++d)
        mx = fmaxf(mx, __shfl(s, mm6 * 6 + ((nn + d) % 6), 64));
      float e = __expf(s - mx);
      float sm = e;
      #pragma unroll
      for (int d = 1; d < 6; ++d)
        sm += __shfl(e, mm6 * 6 + ((nn + d) % 6), 64);
      float a = e / sm;
      attnl[bi][lane] = a;
      if (m == 0) attnO[((size_t)t * 32 + (b0 + bi)) * 36 + lane] = a;
    }
    LBAR();

    // ================= Phase C: A_comm + H_new, 4 batches ===================
    if (tid < 256) {
      #pragma unroll
      for (int bi = 0; bi < 4; ++bi) {
        float ac = 0.f;
        #pragma unroll
        for (int mm = 0; mm < 6; ++mm)
          ac += attnl[bi][mm * 6 + m] * vA[bi][mm];
        float hn = Hin[bi][tid] + ac;
        Hl[bi][tid] = hn;
        size_t gi = (((size_t)t * 32 + (b0 + bi)) * 6 + m) * 256 + tid;
        Hseq[gi] = hn;
        Acm[gi]  = ac;
      }
    }
    LBAR();
  }
}

// ---------------------------------------------------------------------------
// K3: out[b,t,:] = concat(Hseq[t,b,4,:], Hseq[t,b,5,:]) @ W_out + b_out
// ---------------------------------------------------------------------------
__global__ __launch_bounds__(256) void rim_out(
    const float* __restrict__ Hseq, const float* __restrict__ Wout,
    const float* __restrict__ bout, float* __restrict__ out0)
{
  __shared__ float hrow[4][512];
  const int tid = threadIdx.x;
  const int row0 = blockIdx.x * 4;
  for (int i = tid; i < 4 * 512; i += 256) {
    int r = i >> 9, j = i & 511;
    int rb = row0 + r; int b = rb >> 9, t = rb & 511;
    hrow[r][j] = Hseq[((size_t)(t * 32 + b) * 6 + 4 + (j >> 8)) * 256 + (j & 255)];
  }
  __syncthreads();
  const int r = tid >> 6, o = tid & 63;
  const int rb = row0 + r;
  float s = bout[o];
  const float* hp = hrow[r];
  const float* wp = Wout + o;
  #pragma unroll 8
  for (int j = 0; j < 512; ++j) s += hp[j] * wp[(size_t)j * 64];
  out0[(size_t)rb * 64 + o] = s;
}

// ---------------------------------------------------------------------------
// Fallback (round-1 monolithic loop, one block per batch)
// ---------------------------------------------------------------------------
__global__ __launch_bounds__(512) void rim_loop(
    const float* __restrict__ x,
    const float* __restrict__ Vr, const float* __restrict__ WV,
    const float* __restrict__ Wout, const float* __restrict__ bout,
    const float* __restrict__ bip, const float* __restrict__ cbias,
    const float* __restrict__ Ut, const float* __restrict__ WQt, const float* __restrict__ WKt,
    const float* __restrict__ Weff,
    float* __restrict__ out0, float* __restrict__ Hseq,
    float* __restrict__ Acm, float* __restrict__ attnO)
{
  __shared__ float Hl[6][256];
  __shared__ float Hin[6][256];
  __shared__ float biasl[6][256];
  __shared__ float Vcp[2][6][256];
  __shared__ float tmpUr[6][16];
  __shared__ float Qc[6][16], Kc[6][16];
  __shared__ float attnl[36];
  __shared__ float pout[8][64];
  __shared__ float xl[96];
  __shared__ float inpl[4][256];

  const int b = blockIdx.x;
  const int tid = threadIdx.x;
  const int wid = tid >> 5, lane = tid & 31;

  for (int i = tid; i < 1536; i += 512) {
    int m = i >> 8, h = i & 255;
    biasl[m][h] = bip[i] + cbias[i];
    Hl[m][h] = 0.f;
  }
  __syncthreads();

  for (int t = 0; t < TT; ++t) {
    if (tid < 96) xl[tid] = x[(b * TT + t) * II + tid];
    __syncthreads();
    for (int mh = tid; mh < 1024; mh += 512) {
      int m = mh >> 8, h = mh & 255;
      const int base = (m == 0) ? 0 : (m == 1) ? 8192 : (m == 2) ? 16384 : 32768;
      const int cnt  = (m < 2) ? 32 : 64;
      const int xoff = (m < 2) ? 64 : 0;
      float a = 0.f;
      for (int i = 0; i < cnt; ++i) a += xl[xoff + i] * Weff[base + i * 256 + h];
      inpl[m][h] = a;
    }

    for (int pq = wid; pq < 96; pq += 16) {
      int m = pq >> 4, r = pq & 15;
      const float* up = Ut + (m * 16 + r) * 256;
      float s = 0.f;
      #pragma unroll
      for (int h = lane; h < 256; h += 32) s += Hl[m][h] * up[h];
      #pragma unroll
      for (int off = 16; off > 0; off >>= 1) s += __shfl_down(s, off, 32);
      if (lane == 0) tmpUr[m][r] = s;
    }
    __syncthreads();

    for (int mh = tid; mh < 1536; mh += 512) {
      int m = mh >> 8, h = mh & 255;
      float rec = 0.f;
      const float* vp = Vr + m * 4096 + h;
      #pragma unroll
      for (int r = 0; r < 16; ++r) rec += tmpUr[m][r] * vp[r * 256];
      float pre = (m < 4) ? inpl[m][h] : 0.f;
      Hin[m][h] = tanhf(pre + rec + biasl[m][h]);
    }
    __syncthreads();

    for (int pq = wid; pq < 192; pq += 16) {
      int q = pq % 96;
      int m = q >> 4, k = q & 15;
      const float* wp = ((pq < 96) ? WQt : WKt) + (m * 16 + k) * 256;
      float s = 0.f;
      #pragma unroll
      for (int h = lane; h < 256; h += 32) s += Hin[m][h] * wp[h];
      #pragma unroll
      for (int off = 16; off > 0; off >>= 1) s += __shfl_down(s, off, 32);
      if (lane == 0) { if (pq < 96) Qc[m][k] = s; else Kc[m][k] = s; }
    }

    {
      const int h_out = tid & 255, half = tid >> 8;
      for (int m = 0; m < 6; ++m) {
        const float* wv = WV + ((size_t)(m * 256 + half * 128)) * 256 + h_out;
        const float* hv = &Hin[m][half * 128];
        float s = 0.f;
        #pragma unroll 8
        for (int j = 0; j < 128; ++j) s += hv[j] * wv[(size_t)j * 256];
        Vcp[half][m][h_out] = s;
      }
    }
    __syncthreads();

    if (tid < 36) {
      int m = tid / 6, n = tid % 6;
      float s = 0.f;
      #pragma unroll
      for (int k = 0; k < 16; ++k) s += Qc[m][k] * Kc[n][k];
      attnl[tid] = s * 0.25f;
    }
    __syncthreads();
    if (tid < 6) {
      int m = tid;
      float mx = -1e30f;
      #pragma unroll
      for (int n = 0; n < 6; ++n) mx = fmaxf(mx, attnl[m * 6 + n]);
      float e[6], sm = 0.f;
      #pragma unroll
      for (int n = 0; n < 6; ++n) { e[n] = expf(attnl[m * 6 + n] - mx); sm += e[n]; }
      float inv = 1.f / sm;
      #pragma unroll
      for (int n = 0; n < 6; ++n) attnl[m * 6 + n] = e[n] * inv;
    }
    __syncthreads();
    if (tid < 36) attnO[(size_t)(t * 32 + b) * 36 + tid] = attnl[tid];

    for (int mh = tid; mh < 1536; mh += 512) {
      int n = mh >> 8, h = mh & 255;
      float ac = 0.f;
      #pragma unroll
      for (int m = 0; m < 6; ++m)
        ac += attnl[m * 6 + n] * (Vcp[0][m][h] + Vcp[1][m][h]);
      float hn = Hin[n][h] + ac;
      Hl[n][h] = hn;
      size_t gi = ((size_t)(t * 32 + b) * 6 + n) * 256 + h;
      Hseq[gi] = hn;
      Acm[gi]  = ac;
    }
    __syncthreads();

    {
      const int o = tid & 63, js = tid >> 6;
      const float* hp = &Hl[4][0];
      const float* wp = Wout + (size_t)(js * 64) * 64 + o;
      float s = 0.f;
      #pragma unroll 8
      for (int jj = 0; jj < 64; ++jj) s += hp[js * 64 + jj] * wp[(size_t)jj * 64];
      pout[js][o] = s;
    }
    __syncthreads();
    if (tid < 64) {
      float s = bout[tid];
      #pragma unroll
      for (int js = 0; js < 8; ++js) s += pout[js][tid];
      out0[(size_t)(b * TT + t) * 64 + tid] = s;
    }
  }
}

// ---------------------------------------------------------------------------
extern "C" void kernel_launch(void* const* d_in, const int* in_sizes, int n_in,
                              void* d_out, int out_size, void* d_ws, size_t ws_size,
                              hipStream_t stream) {
  const float* x    = (const float*)d_in[0];
  const float* W_ip = (const float*)d_in[1];
  const float* b_ip = (const float*)d_in[2];
  const float* U    = (const float*)d_in[3];
  const float* Vr   = (const float*)d_in[4];
  const float* cb   = (const float*)d_in[5];
  const float* Wt   = (const float*)d_in[6];
  const float* Wsn  = (const float*)d_in[7];
  const float* WQ   = (const float*)d_in[8];
  const float* WK   = (const float*)d_in[9];
  const float* WV   = (const float*)d_in[10];
  const float* Wo   = (const float*)d_in[11];
  const float* bo   = (const float*)d_in[12];

  float* out  = (float*)d_out;
  float* Hseq = out + O_HSEQ;
  float* Ain  = out + O_AIN;
  float* Acm  = out + O_ACM;
  float* attn = out + O_ATTN;

  float* ws   = (float*)d_ws;
  float* Weff = ws + WS_WEFF;
  float* Ut   = ws + WS_UT;
  float* WQt  = ws + WS_WQT;
  float* WKt  = ws + WS_WKT;

  hipLaunchKernelGGL(rim_weff, dim3(288), dim3(256), 0, stream,
                     Wt, Wsn, W_ip, U, WQ, WK, Weff, Ut, WQt, WKt);
  hipLaunchKernelGGL(rim_pre, dim3(1024), dim3(256), 0, stream,
                     x, Wt, Wsn, Ain);

  if (ws_size >= (size_t)WS_COOP_FLOATS * sizeof(float)) {
    float* VcG = ws + WS_VC;
    float* QKG = ws + WS_QK;
    unsigned* seqG = (unsigned*)(ws + WS_FLAG);
    hipMemsetAsync((void*)seqG, 0, 256 * sizeof(unsigned), stream);

    void* args[] = { (void*)&x, (void*)&Vr, (void*)&WV, (void*)&b_ip, (void*)&cb,
                     (void*)&Ut, (void*)&WQt, (void*)&WKt, (void*)&Weff,
                     (void*)&VcG, (void*)&QKG, (void*)&seqG,
                     (void*)&Hseq, (void*)&Acm, (void*)&attn };
    hipLaunchCooperativeKernel((void*)rim_step, dim3(48), dim3(512), args, 0, stream);

    hipLaunchKernelGGL(rim_out, dim3(4096), dim3(256), 0, stream,
                       Hseq, Wo, bo, out);
  } else {
    hipLaunchKernelGGL(rim_loop, dim3(32), dim3(512), 0, stream,
                       x, Vr, WV, Wo, bo, b_ip, cb, Ut, WQt, WKt, Weff,
                       out, Hseq, Acm, attn);
  }
}

// Round 10
// 2797.183 us; speedup vs baseline: 2.2121x; 2.2121x over previous
//
#include <hip/hip_runtime.h>
#include <math.h>

// Problem constants
#define BB 32
#define TT 512
#define II 96

// d_out region offsets (floats)
#define O_HSEQ  1048576
#define O_AIN   26214400
#define O_ACM   51380224
#define O_ATTN  76546048

// ws layout (floats)
#define WS_WEFF 0
#define WS_UT   49152
#define WS_WQT  73728
#define WS_WKT  98304
#define WS_VC   122880          /* full Vc [2][32][6][256] = 98304 */
#define WS_QK   221184          /* [2][32][192] = 12288 */
#define WS_FLAG 233472          /* 512 seq words [b*16+m] */
#define WS_PRBF 233984          /* 192 probe flag slots */
#define WS_PRBD 234176          /* 192 probe data slots */
#define WS_BMP  234368          /* 5 rounds x 192 bitmap words */
#define WS_NONCE 235328         /* 32 per-batch nonce words */
#define WS_COOP_FLOATS 235360

// lgkm-only barrier: orders LDS producer->consumer without draining vmcnt
#define LBAR() asm volatile("s_waitcnt lgkmcnt(0)\n\ts_barrier" ::: "memory")

// ---- SYSTEM-scope (IF) primitives: slow but mapping-independent (proven R2-R8) ----
__device__ __forceinline__ float sysldf(const float* p) {
  return __hip_atomic_load(p, __ATOMIC_RELAXED, __HIP_MEMORY_SCOPE_SYSTEM);
}
__device__ __forceinline__ void sysstf(float* p, float v) {
  __hip_atomic_store(p, v, __ATOMIC_RELAXED, __HIP_MEMORY_SCOPE_SYSTEM);
}
__device__ __forceinline__ unsigned sysld32(const unsigned* p) {
  return __hip_atomic_load(p, __ATOMIC_RELAXED, __HIP_MEMORY_SCOPE_SYSTEM);
}
__device__ __forceinline__ void sysst32(unsigned* p, unsigned v) {
  __hip_atomic_store(p, v, __ATOMIC_RELAXED, __HIP_MEMORY_SCOPE_SYSTEM);
}

// ---- L2-path primitives: plain write-through store + sc0 (L1-bypass) load ----
__device__ __forceinline__ unsigned ldl2u(const unsigned* p) {
  unsigned v;
  asm volatile("global_load_dword %0, %1, off sc0\n\ts_waitcnt vmcnt(0)"
               : "=&v"(v) : "v"(p) : "memory");
  return v;
}
__device__ __forceinline__ void ldl2x6(
    float& d0, float& d1, float& d2, float& d3, float& d4, float& d5,
    const float* p0, const float* p1, const float* p2,
    const float* p3, const float* p4, const float* p5) {
  asm volatile(
    "global_load_dword %0, %6, off sc0\n\t"
    "global_load_dword %1, %7, off sc0\n\t"
    "global_load_dword %2, %8, off sc0\n\t"
    "global_load_dword %3, %9, off sc0\n\t"
    "global_load_dword %4, %10, off sc0\n\t"
    "global_load_dword %5, %11, off sc0\n\t"
    "s_waitcnt vmcnt(0)"
    : "=&v"(d0), "=&v"(d1), "=&v"(d2), "=&v"(d3), "=&v"(d4), "=&v"(d5)
    : "v"(p0), "v"(p1), "v"(p2), "v"(p3), "v"(p4), "v"(p5)
    : "memory");
  __builtin_amdgcn_sched_barrier(0);
}
__device__ __forceinline__ void ldl2x7(
    float& d0, float& d1, float& d2, float& d3, float& d4, float& d5, float& d6,
    const float* p0, const float* p1, const float* p2, const float* p3,
    const float* p4, const float* p5, const float* p6) {
  asm volatile(
    "global_load_dword %0, %7, off sc0\n\t"
    "global_load_dword %1, %8, off sc0\n\t"
    "global_load_dword %2, %9, off sc0\n\t"
    "global_load_dword %3, %10, off sc0\n\t"
    "global_load_dword %4, %11, off sc0\n\t"
    "global_load_dword %5, %12, off sc0\n\t"
    "global_load_dword %6, %13, off sc0\n\t"
    "s_waitcnt vmcnt(0)"
    : "=&v"(d0), "=&v"(d1), "=&v"(d2), "=&v"(d3), "=&v"(d4), "=&v"(d5), "=&v"(d6)
    : "v"(p0), "v"(p1), "v"(p2), "v"(p3), "v"(p4), "v"(p5), "v"(p6)
    : "memory");
  __builtin_amdgcn_sched_barrier(0);
}

// ---------------------------------------------------------------------------
// K0: build Weff[m] = W_in[m] @ W_ip[m]  (m=0..3) and pre-transpose U, W_Q, W_K
// ---------------------------------------------------------------------------
__global__ __launch_bounds__(256) void rim_weff(
    const float* __restrict__ Wtask, const float* __restrict__ Wsens,
    const float* __restrict__ Wip,
    const float* __restrict__ U, const float* __restrict__ WQ, const float* __restrict__ WK,
    float* __restrict__ Weff, float* __restrict__ Ut, float* __restrict__ WQt, float* __restrict__ WKt)
{
  __shared__ float row[256];
  const int bidx = blockIdx.x;
  const int tid = threadIdx.x;
  if (bidx < 192) {
    int m, i;
    if (bidx < 32)       { m = 0; i = bidx; }
    else if (bidx < 64)  { m = 1; i = bidx - 32; }
    else if (bidx < 128) { m = 2; i = bidx - 64; }
    else                 { m = 3; i = bidx - 128; }
    row[tid] = (m < 2) ? Wtask[(m * 32 + i) * 256 + tid]
                       : Wsens[((m - 2) * 64 + i) * 256 + tid];
    __syncthreads();
    float acc = 0.f;
    const float* wip = Wip + m * 65536 + tid;
    #pragma unroll 8
    for (int j = 0; j < 256; ++j) acc += row[j] * wip[j * 256];
    const int base = (m == 0) ? 0 : (m == 1) ? 8192 : (m == 2) ? 16384 : 32768;
    Weff[base + i * 256 + tid] = acc;
  } else {
    const int p = bidx - 192;       // 0..95
    const int m = p >> 4, r = p & 15;
    Ut [(m * 16 + r) * 256 + tid] = U [m * 4096 + tid * 16 + r];
    WQt[(m * 16 + r) * 256 + tid] = WQ[m * 4096 + tid * 16 + r];
    WKt[(m * 16 + r) * 256 + tid] = WK[m * 4096 + tid * 16 + r];
  }
}

// ---------------------------------------------------------------------------
// K1: parallel Ain_seq output (independent of the recurrence)
// ---------------------------------------------------------------------------
__global__ __launch_bounds__(256) void rim_pre(
    const float* __restrict__ x,
    const float* __restrict__ Wtask, const float* __restrict__ Wsens,
    float* __restrict__ Ain)
{
  __shared__ float xr[16][96];
  const int tid = threadIdx.x;
  const int rb0 = blockIdx.x * 16;
  for (int idx = tid; idx < 16 * 96; idx += 256) {
    int r = idx / 96, c = idx % 96;
    int rb = rb0 + r; int t = rb >> 5, b = rb & 31;
    xr[r][c] = x[(b * TT + t) * II + c];
  }
  __syncthreads();
  const int h = tid;
  float acc[16];

  for (int m = 0; m < 4; ++m) {
    const int cnt  = (m < 2) ? 32 : 64;
    const int xoff = (m < 2) ? 64 : 0;
    const float* W = (m < 2) ? (Wtask + m * 32 * 256) : (Wsens + (m - 2) * 64 * 256);
    #pragma unroll
    for (int r = 0; r < 16; ++r) acc[r] = 0.f;
    for (int i = 0; i < cnt; ++i) {
      float w = W[i * 256 + h];
      #pragma unroll
      for (int r = 0; r < 16; ++r) acc[r] += xr[r][xoff + i] * w;
    }
    #pragma unroll
    for (int r = 0; r < 16; ++r) {
      int rb = rb0 + r; int t = rb >> 5, b = rb & 31;
      Ain[((t * 32 + b) * 6 + m) * 256 + h] = acc[r];
    }
  }
  #pragma unroll
  for (int r = 0; r < 16; ++r) {
    int rb = rb0 + r; int t = rb >> 5, b = rb & 31;
    Ain[((t * 32 + b) * 6 + 4) * 256 + h] = 0.f;
    Ain[((t * 32 + b) * 6 + 5) * 256 + h] = 0.f;
  }
}

// ---------------------------------------------------------------------------
// K2: cooperative recurrence. 192 blocks, remapped: bid = (b%8) + 8*(m + 6*(b/8))
// so a batch's 6 blocks land on one XCD under round-robin dispatch.
// Fast path (shared-L2 mailbox: plain stores + sc0 loads) engaged ONLY if an
// empirical coherence probe (nonce-tagged, bounded spins, SYSTEM-committed)
// passes unanimously; otherwise the R5-proven SYSTEM-scope path. No unbounded
// spin ever depends on an unverified property -> deadlock-free.
// ---------------------------------------------------------------------------
__global__ __launch_bounds__(512, 2) void rim_step(
    const float* __restrict__ x,
    const float* __restrict__ Vr, const float* __restrict__ WV,
    const float* __restrict__ bip, const float* __restrict__ cbias,
    const float* __restrict__ UtW, const float* __restrict__ WQtW,
    const float* __restrict__ WKtW, const float* __restrict__ WeffW,
    float* __restrict__ VcG, float* __restrict__ QKG,
    unsigned* __restrict__ seqG,
    unsigned* __restrict__ prbF, unsigned* __restrict__ prbD,
    unsigned* __restrict__ bmpG, unsigned* __restrict__ nonceG,
    float* __restrict__ Hseq, float* __restrict__ Acm, float* __restrict__ attnO)
{
  __shared__ __align__(16) float Hl[256];
  __shared__ __align__(16) float Hin[256];
  __shared__ float biasl[256];
  __shared__ float Utl[16][257];    // +1 pad
  __shared__ float Vrl[16][257];
  __shared__ float WQtl[16][257];
  __shared__ float WKtl[16][257];
  __shared__ float Weffl[64][256];
  __shared__ float inpl[2][256];
  __shared__ float xl[2][96];
  __shared__ float Vcp1[256];
  __shared__ float tmpUr[16];
  __shared__ float attnl[40];
  __shared__ float qkl[192];
  __shared__ int fastS;

  const int bid = blockIdx.x;
  // decode remap: bid = (b%8) + 8*(m + 6*(b/8))
  const int rrm = bid & 7, qq = bid >> 3;
  const int m = qq % 6;             // 0..5
  const int b = rrm + 8 * (qq / 6); // 0..31
  const int tid = threadIdx.x;
  const int g32 = tid >> 5, l32 = tid & 31;
  const int h_out = tid & 255, p = tid >> 8;
  const int g16 = tid >> 4, l16 = tid & 15;
  const int w64 = tid >> 6, lane = tid & 63;

  const int base = (m == 0) ? 0 : (m == 1) ? 8192 : (m == 2) ? 16384 : 32768;
  const int cnt  = (m < 2) ? 32 : 64;
  const int xoff = (m < 2) ? 64 : 0;

  // ---- init: stage per-module weights into LDS ----
  for (int i = tid; i < 4096; i += 512) {
    int r = i >> 8, c = i & 255;
    Utl [r][c] = UtW [m * 4096 + i];
    Vrl [r][c] = Vr  [m * 4096 + i];
    WQtl[r][c] = WQtW[m * 4096 + i];
    WKtl[r][c] = WKtW[m * 4096 + i];
  }
  if (m < 4)
    for (int i = tid; i < cnt * 256; i += 512)
      ((float*)Weffl)[i] = WeffW[base + i];
  if (tid < 256) {
    biasl[tid] = bip[m * 256 + tid] + cbias[m * 256 + tid];
    Hl[tid] = 0.f;
  }
  float xreg = 0.f;
  if (m < 4 && tid < 96) {
    xl[0][tid] = x[((size_t)b * TT + 0) * II + tid];
    xreg       = x[((size_t)b * TT + 1) * II + tid];
  }
  // W_V half-column: w[j] = WV[m][p*128+j][h_out]
  float w[128];
  #pragma unroll
  for (int j = 0; j < 128; ++j)
    w[j] = WV[((size_t)(m * 256 + p * 128 + j)) * 256 + h_out];

  // ================== coherence probe (tid==0, bounded) ==================
  if (tid == 0) {
    // -- per-batch nonce (replay-unique; leader m==0; SYSTEM words are
    //    memset-fresh each launch so stale L2 lines can't fake these) --
    unsigned nonce;
    if (m == 0) {
      unsigned long long tt = clock64();
      nonce = (unsigned)(tt ^ (tt >> 17) ^ 0x5bd1e995u) & 0x7FFFFFFFu;
      if (nonce == 0) nonce = 1;
      sysst32(&nonceG[b], 0x80000000u | nonce);
    } else {
      unsigned e;
      do { e = sysld32(&nonceG[b]); } while (!(e & 0x80000000u));
      nonce = e & 0x7FFFFFFFu;
    }
    const unsigned pbase = nonce * 2654435761u;
    bool ok = true;

    // -- round 0: presence (plain store -> drain -> sc0 spin, bounded) --
    {
      unsigned myp = (pbase + (unsigned)bid * 193u + 0x11110000u) | 1u;
      *(volatile unsigned*)&prbF[bid] = myp;
      asm volatile("s_waitcnt vmcnt(0)" ::: "memory");
      unsigned seen = 0;
      for (int it = 0; it < 3000 && seen != 0x3Fu; ++it) {
        int mm = it % 6;
        if (!(seen & (1u << mm))) {
          int pbm = (b & 7) + 8 * (mm + 6 * (b >> 3));
          unsigned want = (pbase + (unsigned)pbm * 193u + 0x11110000u) | 1u;
          if (ldl2u(&prbF[pbm]) == want) seen |= (1u << mm);
        }
      }
      sysst32(&bmpG[0 * 192 + bid], 0x40000000u | seen);
      for (int mm = 0; mm < 6; ++mm) {
        int pbm = (b & 7) + 8 * (mm + 6 * (b >> 3));
        unsigned e;
        do { e = sysld32(&bmpG[0 * 192 + pbm]); } while (!(e & 0x40000000u));
        ok = ok && ((e & 0x3Fu) == 0x3Fu);
      }
    }

    // -- rounds 1..3: data-then-flag ordering (the loop's exact protocol).
    //    Flag visible but data stale => hard fail (cross-L2 eviction trap). --
    for (int r = 1; r <= 3; ++r) {
      if (ok) {
        unsigned dp = (pbase + (unsigned)bid * 97u + (unsigned)r * 0x010F0000u) | 1u;
        unsigned fp = (pbase + (unsigned)bid * 57u + (unsigned)r * 0x00F10000u + 0x20000000u) | 1u;
        *(volatile unsigned*)&prbD[bid] = dp;
        asm volatile("s_waitcnt vmcnt(0)" ::: "memory");
        *(volatile unsigned*)&prbF[bid] = fp;
        asm volatile("s_waitcnt vmcnt(0)" ::: "memory");
        unsigned good = 0, fail = 0;
        for (int it = 0; it < 1500 && good != 0x3Fu && !fail; ++it) {
          int mm = it % 6;
          if (!(good & (1u << mm))) {
            int pbm = (b & 7) + 8 * (mm + 6 * (b >> 3));
            unsigned fexp = (pbase + (unsigned)pbm * 57u + (unsigned)r * 0x00F10000u + 0x20000000u) | 1u;
            if (ldl2u(&prbF[pbm]) == fexp) {
              unsigned dexp = (pbase + (unsigned)pbm * 97u + (unsigned)r * 0x010F0000u) | 1u;
              if (ldl2u(&prbD[pbm]) == dexp) good |= (1u << mm);
              else fail = 1;
            }
          }
        }
        sysst32(&bmpG[r * 192 + bid], 0x40000000u | good | (fail ? 0x80u : 0u));
        for (int mm = 0; mm < 6; ++mm) {
          int pbm = (b & 7) + 8 * (mm + 6 * (b >> 3));
          unsigned e;
          do { e = sysld32(&bmpG[r * 192 + pbm]); } while (!(e & 0x40000000u));
          ok = ok && ((e & 0xBFu) == 0x3Fu);
        }
      }
    }

    // -- round 4 (fast only): plain-zero own seq slot (kills stale L2 lines
    //    from prior replays), then SYSTEM rendezvous before anyone polls. --
    if (ok) {
      *(volatile unsigned*)&seqG[b * 16 + m] = 0u;
      asm volatile("s_waitcnt vmcnt(0)" ::: "memory");
      sysst32(&bmpG[4 * 192 + bid], 0x40000000u);
      for (int mm = 0; mm < 6; ++mm) {
        int pbm = (b & 7) + 8 * (mm + 6 * (b >> 3));
        unsigned e;
        do { e = sysld32(&bmpG[4 * 192 + pbm]); } while (!(e & 0x40000000u));
      }
    }
    fastS = ok ? 1 : 0;
  }
  __syncthreads();
  const bool fast = (fastS != 0);

  // inp for t=0
  if (m < 4 && tid < 256) {
    float a = 0.f;
    for (int i = 0; i < cnt; ++i) a += xl[0][xoff + i] * Weffl[i][tid];
    inpl[0][tid] = a;
  }
  __syncthreads();

  for (int t = 0; t < TT; ++t) {
    const int buf = t & 1;
    const unsigned target = (unsigned)(t + 1);
    const int vb6 = (buf * 32 + b) * 6;
    const int qb  = (buf * 32 + b) * 192;

    // x double-buffer: stage x_{t+1}, prefetch x_{t+2}
    if (m < 4 && tid < 96) {
      xl[(t + 1) & 1][tid] = xreg;
      xreg = (t + 2 < TT) ? x[((size_t)b * TT + t + 2) * II + tid] : 0.f;
    }

    // ---- P1: tmpUr[r] = sum_h Hl[h]*U[m][h][r] ----
    {
      float s = 0.f;
      const float* up = &Utl[g32][0];
      #pragma unroll
      for (int h = l32; h < 256; h += 32) s += Hl[h] * up[h];
      #pragma unroll
      for (int off = 16; off > 0; off >>= 1) s += __shfl_down(s, off, 32);
      if (l32 == 0) tmpUr[g32] = s;
    }
    LBAR();  // B1

    // ---- P2: Hin = tanh(inp + rec + bias) ----
    if (tid < 256) {
      float rec = 0.f;
      #pragma unroll
      for (int r = 0; r < 16; ++r) rec += tmpUr[r] * Vrl[r][tid];
      float inp = (m < 4) ? inpl[buf][tid] : 0.f;
      Hin[tid] = tanhf(inp + rec + biasl[tid]);
    }
    LBAR();  // B2

    // ---- P3: QK publish + Vc half-dot; p1 half -> LDS ----
    {
      const int r = g16 & 15;
      const float* wp = (g16 < 16) ? &WQtl[r][0] : &WKtl[r][0];
      float s = 0.f;
      #pragma unroll
      for (int j = 0; j < 16; ++j) { int h = l16 + 16 * j; s += Hin[h] * wp[h]; }
      s += __shfl_down(s, 8, 16);
      s += __shfl_down(s, 4, 16);
      s += __shfl_down(s, 2, 16);
      s += __shfl_down(s, 1, 16);
      if (l16 == 0) {
        float* pq = &QKG[qb + ((g16 < 16) ? 0 : 96) + m * 16 + r];
        if (fast) *(volatile float*)pq = s;
        else      sysstf(pq, s);
      }
    }
    float accVc = 0.f;
    {
      const float4* h4 = (const float4*)&Hin[p * 128];
      #pragma unroll
      for (int q = 0; q < 32; ++q) {
        float4 hv = h4[q];
        accVc += hv.x * w[4 * q] + hv.y * w[4 * q + 1]
               + hv.z * w[4 * q + 2] + hv.w * w[4 * q + 3];
      }
    }
    if (p == 1) Vcp1[h_out] = accVc;
    LBAR();  // B3a — Vcp1 ready

    // ---- publish full own Vc ----
    float vown = 0.f;
    if (tid < 256) {
      vown = accVc + Vcp1[tid];
      float* pp = &VcG[(vb6 + m) * 256 + tid];
      if (fast) *(volatile float*)pp = vown;
      else      sysstf(pp, vown);
    }
    asm volatile("s_waitcnt vmcnt(0)" ::: "memory");  // stores at coherence pt
    LBAR();  // B3 — all waves drained
    if (tid == 0) {
      unsigned* ps = &seqG[b * 16 + m];
      if (fast) *(volatile unsigned*)ps = target;
      else      sysst32(ps, target);
    }

    // ---- overlap: waves 4-7 compute inp(t+1); wave0 lanes<6 poll ----
    if (tid >= 256 && m < 4) {
      const int h = tid - 256, nb = (t + 1) & 1;
      float a = 0.f;
      for (int i = 0; i < cnt; ++i) a += xl[nb][xoff + i] * Weffl[i][h];
      inpl[nb][h] = a;
    }
    if (w64 == 0 && lane < 6) {
      const unsigned* ps = &seqG[b * 16 + lane];
      if (fast) { while (ldl2u(ps)   < target) { } }
      else      { while (sysld32(ps) < target) { } }
    }
    LBAR();  // B4 — all peers published

    // ---- bulk loads: 6 Vc (own overwritten) + qk (tid<192) ----
    float vC[6]; float qv = 0.f;
    if (tid < 192) {
      if (fast) {
        ldl2x7(qv, vC[0], vC[1], vC[2], vC[3], vC[4], vC[5],
               &QKG[qb + tid],
               &VcG[(vb6 + 0) * 256 + tid], &VcG[(vb6 + 1) * 256 + tid],
               &VcG[(vb6 + 2) * 256 + tid], &VcG[(vb6 + 3) * 256 + tid],
               &VcG[(vb6 + 4) * 256 + tid], &VcG[(vb6 + 5) * 256 + tid]);
      } else {
        qv = sysldf(&QKG[qb + tid]);
        #pragma unroll
        for (int mm = 0; mm < 6; ++mm)
          vC[mm] = sysldf(&VcG[(vb6 + mm) * 256 + tid]);
      }
    } else if (tid < 256) {
      if (fast) {
        ldl2x6(vC[0], vC[1], vC[2], vC[3], vC[4], vC[5],
               &VcG[(vb6 + 0) * 256 + tid], &VcG[(vb6 + 1) * 256 + tid],
               &VcG[(vb6 + 2) * 256 + tid], &VcG[(vb6 + 3) * 256 + tid],
               &VcG[(vb6 + 4) * 256 + tid], &VcG[(vb6 + 5) * 256 + tid]);
      } else {
        #pragma unroll
        for (int mm = 0; mm < 6; ++mm)
          vC[mm] = sysldf(&VcG[(vb6 + mm) * 256 + tid]);
      }
    }
    if (tid < 256) vC[m] = vown;   // own value from register
    if (tid < 192) qkl[tid] = qv;
    LBAR();  // B5

    // ---- attention (6 lanes of wave 0) ----
    if (w64 == 0 && lane < 6) {
      float sc[6]; float mx = -1e30f;
      #pragma unroll
      for (int n = 0; n < 6; ++n) {
        float s = 0.f;
        #pragma unroll
        for (int k = 0; k < 16; ++k) s += qkl[lane * 16 + k] * qkl[96 + n * 16 + k];
        sc[n] = s * 0.25f; mx = fmaxf(mx, sc[n]);
      }
      float sm = 0.f;
      #pragma unroll
      for (int n = 0; n < 6; ++n) { sc[n] = expf(sc[n] - mx); sm += sc[n]; }
      float inv = 1.f / sm;
      #pragma unroll
      for (int n = 0; n < 6; ++n) {
        float a = sc[n] * inv;
        attnl[lane * 6 + n] = a;
        if (m == 0) attnO[((size_t)t * 32 + b) * 36 + lane * 6 + n] = a;
      }
    }
    LBAR();  // B6

    // ---- A_comm + H_new ----
    if (tid < 256) {
      float ac = 0.f;
      #pragma unroll
      for (int mm = 0; mm < 6; ++mm) ac += attnl[mm * 6 + m] * vC[mm];
      float hn = Hin[tid] + ac;
      Hl[tid] = hn;
      size_t gi = (((size_t)t * 32 + b) * 6 + m) * 256 + tid;
      Hseq[gi] = hn;
      Acm[gi]  = ac;
    }
    LBAR();  // B7 — Hl ready; output stores drain off the critical path
  }
}

// ---------------------------------------------------------------------------
// K3: out[b,t,:] = concat(Hseq[t,b,4,:], Hseq[t,b,5,:]) @ W_out + b_out
// ---------------------------------------------------------------------------
__global__ __launch_bounds__(256) void rim_out(
    const float* __restrict__ Hseq, const float* __restrict__ Wout,
    const float* __restrict__ bout, float* __restrict__ out0)
{
  __shared__ float hrow[4][512];
  const int tid = threadIdx.x;
  const int row0 = blockIdx.x * 4;
  for (int i = tid; i < 4 * 512; i += 256) {
    int r = i >> 9, j = i & 511;
    int rb = row0 + r; int b = rb >> 9, t = rb & 511;
    hrow[r][j] = Hseq[((size_t)(t * 32 + b) * 6 + 4 + (j >> 8)) * 256 + (j & 255)];
  }
  __syncthreads();
  const int r = tid >> 6, o = tid & 63;
  const int rb = row0 + r;
  float s = bout[o];
  const float* hp = hrow[r];
  const float* wp = Wout + o;
  #pragma unroll 8
  for (int j = 0; j < 512; ++j) s += hp[j] * wp[(size_t)j * 64];
  out0[(size_t)rb * 64 + o] = s;
}

// ---------------------------------------------------------------------------
// Fallback (round-1 monolithic loop, one block per batch)
// ---------------------------------------------------------------------------
__global__ __launch_bounds__(512) void rim_loop(
    const float* __restrict__ x,
    const float* __restrict__ Vr, const float* __restrict__ WV,
    const float* __restrict__ Wout, const float* __restrict__ bout,
    const float* __restrict__ bip, const float* __restrict__ cbias,
    const float* __restrict__ Ut, const float* __restrict__ WQt, const float* __restrict__ WKt,
    const float* __restrict__ Weff,
    float* __restrict__ out0, float* __restrict__ Hseq,
    float* __restrict__ Acm, float* __restrict__ attnO)
{
  __shared__ float Hl[6][256];
  __shared__ float Hin[6][256];
  __shared__ float biasl[6][256];
  __shared__ float Vcp[2][6][256];
  __shared__ float tmpUr[6][16];
  __shared__ float Qc[6][16], Kc[6][16];
  __shared__ float attnl[36];
  __shared__ float pout[8][64];
  __shared__ float xl[96];
  __shared__ float inpl[4][256];

  const int b = blockIdx.x;
  const int tid = threadIdx.x;
  const int wid = tid >> 5, lane = tid & 31;

  for (int i = tid; i < 1536; i += 512) {
    int m = i >> 8, h = i & 255;
    biasl[m][h] = bip[i] + cbias[i];
    Hl[m][h] = 0.f;
  }
  __syncthreads();

  for (int t = 0; t < TT; ++t) {
    if (tid < 96) xl[tid] = x[(b * TT + t) * II + tid];
    __syncthreads();
    for (int mh = tid; mh < 1024; mh += 512) {
      int m = mh >> 8, h = mh & 255;
      const int base = (m == 0) ? 0 : (m == 1) ? 8192 : (m == 2) ? 16384 : 32768;
      const int cnt  = (m < 2) ? 32 : 64;
      const int xoff = (m < 2) ? 64 : 0;
      float a = 0.f;
      for (int i = 0; i < cnt; ++i) a += xl[xoff + i] * Weff[base + i * 256 + h];
      inpl[m][h] = a;
    }

    for (int pq = wid; pq < 96; pq += 16) {
      int m = pq >> 4, r = pq & 15;
      const float* up = Ut + (m * 16 + r) * 256;
      float s = 0.f;
      #pragma unroll
      for (int h = lane; h < 256; h += 32) s += Hl[m][h] * up[h];
      #pragma unroll
      for (int off = 16; off > 0; off >>= 1) s += __shfl_down(s, off, 32);
      if (lane == 0) tmpUr[m][r] = s;
    }
    __syncthreads();

    for (int mh = tid; mh < 1536; mh += 512) {
      int m = mh >> 8, h = mh & 255;
      float rec = 0.f;
      const float* vp = Vr + m * 4096 + h;
      #pragma unroll
      for (int r = 0; r < 16; ++r) rec += tmpUr[m][r] * vp[r * 256];
      float pre = (m < 4) ? inpl[m][h] : 0.f;
      Hin[m][h] = tanhf(pre + rec + biasl[m][h]);
    }
    __syncthreads();

    for (int pq = wid; pq < 192; pq += 16) {
      int q = pq % 96;
      int m = q >> 4, k = q & 15;
      const float* wp = ((pq < 96) ? WQt : WKt) + (m * 16 + k) * 256;
      float s = 0.f;
      #pragma unroll
      for (int h = lane; h < 256; h += 32) s += Hin[m][h] * wp[h];
      #pragma unroll
      for (int off = 16; off > 0; off >>= 1) s += __shfl_down(s, off, 32);
      if (lane == 0) { if (pq < 96) Qc[m][k] = s; else Kc[m][k] = s; }
    }

    {
      const int h_out = tid & 255, half = tid >> 8;
      for (int m = 0; m < 6; ++m) {
        const float* wv = WV + ((size_t)(m * 256 + half * 128)) * 256 + h_out;
        const float* hv = &Hin[m][half * 128];
        float s = 0.f;
        #pragma unroll 8
        for (int j = 0; j < 128; ++j) s += hv[j] * wv[(size_t)j * 256];
        Vcp[half][m][h_out] = s;
      }
    }
    __syncthreads();

    if (tid < 36) {
      int m = tid / 6, n = tid % 6;
      float s = 0.f;
      #pragma unroll
      for (int k = 0; k < 16; ++k) s += Qc[m][k] * Kc[n][k];
      attnl[tid] = s * 0.25f;
    }
    __syncthreads();
    if (tid < 6) {
      int m = tid;
      float mx = -1e30f;
      #pragma unroll
      for (int n = 0; n < 6; ++n) mx = fmaxf(mx, attnl[m * 6 + n]);
      float e[6], sm = 0.f;
      #pragma unroll
      for (int n = 0; n < 6; ++n) { e[n] = expf(attnl[m * 6 + n] - mx); sm += e[n]; }
      float inv = 1.f / sm;
      #pragma unroll
      for (int n = 0; n < 6; ++n) attnl[m * 6 + n] = e[n] * inv;
    }
    __syncthreads();
    if (tid < 36) attnO[(size_t)(t * 32 + b) * 36 + tid] = attnl[tid];

    for (int mh = tid; mh < 1536; mh += 512) {
      int n = mh >> 8, h = mh & 255;
      float ac = 0.f;
      #pragma unroll
      for (int m = 0; m < 6; ++m)
        ac += attnl[m * 6 + n] * (Vcp[0][m][h] + Vcp[1][m][h]);
      float hn = Hin[n][h] + ac;
      Hl[n][h] = hn;
      size_t gi = ((size_t)(t * 32 + b) * 6 + n) * 256 + h;
      Hseq[gi] = hn;
      Acm[gi]  = ac;
    }
    __syncthreads();

    {
      const int o = tid & 63, js = tid >> 6;
      const float* hp = &Hl[4][0];
      const float* wp = Wout + (size_t)(js * 64) * 64 + o;
      float s = 0.f;
      #pragma unroll 8
      for (int jj = 0; jj < 64; ++jj) s += hp[js * 64 + jj] * wp[(size_t)jj * 64];
      pout[js][o] = s;
    }
    __syncthreads();
    if (tid < 64) {
      float s = bout[tid];
      #pragma unroll
      for (int js = 0; js < 8; ++js) s += pout[js][tid];
      out0[(size_t)(b * TT + t) * 64 + tid] = s;
    }
  }
}

// ---------------------------------------------------------------------------
extern "C" void kernel_launch(void* const* d_in, const int* in_sizes, int n_in,
                              void* d_out, int out_size, void* d_ws, size_t ws_size,
                              hipStream_t stream) {
  const float* x    = (const float*)d_in[0];
  const float* W_ip = (const float*)d_in[1];
  const float* b_ip = (const float*)d_in[2];
  const float* U    = (const float*)d_in[3];
  const float* Vr   = (const float*)d_in[4];
  const float* cb   = (const float*)d_in[5];
  const float* Wt   = (const float*)d_in[6];
  const float* Wsn  = (const float*)d_in[7];
  const float* WQ   = (const float*)d_in[8];
  const float* WK   = (const float*)d_in[9];
  const float* WV   = (const float*)d_in[10];
  const float* Wo   = (const float*)d_in[11];
  const float* bo   = (const float*)d_in[12];

  float* out  = (float*)d_out;
  float* Hseq = out + O_HSEQ;
  float* Ain  = out + O_AIN;
  float* Acm  = out + O_ACM;
  float* attn = out + O_ATTN;

  float* ws   = (float*)d_ws;
  float* Weff = ws + WS_WEFF;
  float* Ut   = ws + WS_UT;
  float* WQt  = ws + WS_WQT;
  float* WKt  = ws + WS_WKT;

  hipLaunchKernelGGL(rim_weff, dim3(288), dim3(256), 0, stream,
                     Wt, Wsn, W_ip, U, WQ, WK, Weff, Ut, WQt, WKt);
  hipLaunchKernelGGL(rim_pre, dim3(1024), dim3(256), 0, stream,
                     x, Wt, Wsn, Ain);

  if (ws_size >= (size_t)WS_COOP_FLOATS * sizeof(float)) {
    float* VcG = ws + WS_VC;
    float* QKG = ws + WS_QK;
    unsigned* seqG   = (unsigned*)(ws + WS_FLAG);
    unsigned* prbF   = (unsigned*)(ws + WS_PRBF);
    unsigned* prbD   = (unsigned*)(ws + WS_PRBD);
    unsigned* bmpG   = (unsigned*)(ws + WS_BMP);
    unsigned* nonceG = (unsigned*)(ws + WS_NONCE);
    // clear seq + probe + bitmap + nonce words each launch (in-graph)
    hipMemsetAsync((void*)seqG, 0,
                   (size_t)(WS_COOP_FLOATS - WS_FLAG) * sizeof(float), stream);

    void* args[] = { (void*)&x, (void*)&Vr, (void*)&WV, (void*)&b_ip, (void*)&cb,
                     (void*)&Ut, (void*)&WQt, (void*)&WKt, (void*)&Weff,
                     (void*)&VcG, (void*)&QKG, (void*)&seqG,
                     (void*)&prbF, (void*)&prbD, (void*)&bmpG, (void*)&nonceG,
                     (void*)&Hseq, (void*)&Acm, (void*)&attn };
    hipLaunchCooperativeKernel((void*)rim_step, dim3(192), dim3(512), args, 0, stream);

    hipLaunchKernelGGL(rim_out, dim3(4096), dim3(256), 0, stream,
                       Hseq, Wo, bo, out);
  } else {
    hipLaunchKernelGGL(rim_loop, dim3(32), dim3(512), 0, stream,
                       x, Vr, WV, Wo, bo, b_ip, cb, Ut, WQt, WKt, Weff,
                       out, Hseq, Acm, attn);
  }
}